// Round 1
// baseline (218.559 us; speedup 1.0000x reference)
//
#include <hip/hip_runtime.h>

namespace {
constexpr int IMG_W = 512, IMG_H = 512;
constexpr int TW = 32, TH = 32;
constexpr int IN_W = TW + 10, IN_H = TH + 10;   // 42
constexpr int S12_STR = 43;                     // float2 stride, bank-balanced
constexpr int H_STR = 33;                       // h-plane stride, bank-balanced
constexpr float C1c = 0.01f * 0.01f;
constexpr float C2c = 0.03f * 0.03f;

// Gaussian(sigma=1.5, K=11), normalized; sum == 1.0
constexpr float GW[11] = {
    1.0283799e-03f, 7.5987582e-03f, 3.6000773e-02f, 1.0936069e-01f,
    2.1300554e-01f, 2.6601172e-01f, 2.1300554e-01f, 1.0936069e-01f,
    3.6000773e-02f, 7.5987582e-03f, 1.0283799e-03f
};
}

__global__ __launch_bounds__(256, 3) void ssim_tile_kernel(
        const float* __restrict__ img1, const float* __restrict__ img2,
        float* __restrict__ partial)
{
    __shared__ float2 s12[IN_H * S12_STR];   // (img1,img2) tile       14448 B
    __shared__ float2 h12[IN_H * H_STR];     // horiz (mu1,mu2)        11088 B
    __shared__ float4 h3 [IN_H * H_STR];     // horiz (aa,bb,ab,_)     22176 B
    __shared__ float  wred[4];

    const int tid = threadIdx.x;
    const size_t base = (size_t)blockIdx.z * (IMG_W * IMG_H);
    const float* p1 = img1 + base;
    const float* p2 = img2 + base;
    const int x0 = blockIdx.x * TW - 5;
    const int y0 = blockIdx.y * TH - 5;

    // ---- Phase 1: global -> LDS (zero-padded halo) ----
    for (int p = tid; p < IN_H * IN_W; p += 256) {
        const int r = p / IN_W;
        const int c = p - r * IN_W;
        const int gy = y0 + r;
        const int gx = x0 + c;
        float a = 0.f, b = 0.f;
        if (gy >= 0 && gy < IMG_H && gx >= 0 && gx < IMG_W) {
            const int off = gy * IMG_W + gx;
            a = p1[off];
            b = p2[off];
        }
        s12[r * S12_STR + c] = make_float2(a, b);
    }
    __syncthreads();

    // ---- Phase 2: horizontal 11-tap pass, sliding window in registers ----
    // 42 rows x 4 col-groups of 8 outputs = 168 active threads
    if (tid < 168) {
        const int r  = tid >> 2;
        const int cb = (tid & 3) * 8;
        float2 v[18];
#pragma unroll
        for (int k = 0; k < 18; ++k) v[k] = s12[r * S12_STR + cb + k];
        float aa[18], bb[18], ab[18];
#pragma unroll
        for (int k = 0; k < 18; ++k) {
            aa[k] = v[k].x * v[k].x;
            bb[k] = v[k].y * v[k].y;
            ab[k] = v[k].x * v[k].y;
        }
#pragma unroll
        for (int j = 0; j < 8; ++j) {
            float m1 = 0.f, m2 = 0.f, sa = 0.f, sb = 0.f, sc = 0.f;
#pragma unroll
            for (int k = 0; k < 11; ++k) {
                const float wk = GW[k];
                m1 = fmaf(wk, v[j + k].x, m1);
                m2 = fmaf(wk, v[j + k].y, m2);
                sa = fmaf(wk, aa[j + k], sa);
                sb = fmaf(wk, bb[j + k], sb);
                sc = fmaf(wk, ab[j + k], sc);
            }
            h12[r * H_STR + cb + j] = make_float2(m1, m2);
            h3 [r * H_STR + cb + j] = make_float4(sa, sb, sc, 0.f);
        }
    }
    __syncthreads();

    // ---- Phase 3: vertical 11-tap pass + SSIM, 4 rows per thread ----
    const int c  = tid & 31;
    const int rb = (tid >> 5) * 4;      // output rows rb..rb+3, h rows rb..rb+13
    float hm1[14], hm2[14], haa[14], hbb[14], hab[14];
#pragma unroll
    for (int k = 0; k < 14; ++k) {
        const float2 t = h12[(rb + k) * H_STR + c];
        const float4 u = h3 [(rb + k) * H_STR + c];
        hm1[k] = t.x; hm2[k] = t.y;
        haa[k] = u.x; hbb[k] = u.y; hab[k] = u.z;
    }
    float lsum = 0.f;
#pragma unroll
    for (int j = 0; j < 4; ++j) {
        float mu1 = 0.f, mu2 = 0.f, saa = 0.f, sbb = 0.f, sab = 0.f;
#pragma unroll
        for (int k = 0; k < 11; ++k) {
            const float wk = GW[k];
            mu1 = fmaf(wk, hm1[j + k], mu1);
            mu2 = fmaf(wk, hm2[j + k], mu2);
            saa = fmaf(wk, haa[j + k], saa);
            sbb = fmaf(wk, hbb[j + k], sbb);
            sab = fmaf(wk, hab[j + k], sab);
        }
        const float mu1s = mu1 * mu1;
        const float mu2s = mu2 * mu2;
        const float mu12 = mu1 * mu2;
        const float sg1  = saa - mu1s;
        const float sg2  = sbb - mu2s;
        const float sg12 = sab - mu12;
        const float num = (2.f * mu12 + C1c) * (2.f * sg12 + C2c);
        const float den = (mu1s + mu2s + C1c) * (sg1 + sg2 + C2c);
        lsum += num / den;
    }

    // ---- Phase 4: block reduction -> per-block partial ----
#pragma unroll
    for (int off = 32; off > 0; off >>= 1)
        lsum += __shfl_down(lsum, off, 64);
    if ((tid & 63) == 0) wred[tid >> 6] = lsum;
    __syncthreads();
    if (tid == 0)
        partial[(blockIdx.z * gridDim.y + blockIdx.y) * gridDim.x + blockIdx.x] =
            wred[0] + wred[1] + wred[2] + wred[3];
}

__global__ __launch_bounds__(256) void ssim_reduce_kernel(
        const float* __restrict__ partial, float* __restrict__ out,
        int n, double inv_total)
{
    double acc = 0.0;
    for (int i = threadIdx.x; i < n; i += 256) acc += (double)partial[i];
#pragma unroll
    for (int off = 32; off > 0; off >>= 1)
        acc += __shfl_down(acc, off, 64);
    __shared__ double ws[4];
    if ((threadIdx.x & 63) == 0) ws[threadIdx.x >> 6] = acc;
    __syncthreads();
    if (threadIdx.x == 0)
        out[0] = (float)((ws[0] + ws[1] + ws[2] + ws[3]) * inv_total);
}

extern "C" void kernel_launch(void* const* d_in, const int* in_sizes, int n_in,
                              void* d_out, int out_size, void* d_ws, size_t ws_size,
                              hipStream_t stream)
{
    const float* img1 = (const float*)d_in[0];
    const float* img2 = (const float*)d_in[1];
    float* partial = (float*)d_ws;

    const int nch = in_sizes[0] / (IMG_W * IMG_H);      // 16*3 = 48
    dim3 grid(IMG_W / TW, IMG_H / TH, nch);             // 16 x 16 x 48
    ssim_tile_kernel<<<grid, 256, 0, stream>>>(img1, img2, partial);

    const int nblk = (IMG_W / TW) * (IMG_H / TH) * nch; // 12288
    const double inv_total = 1.0 / (double)in_sizes[0];
    ssim_reduce_kernel<<<1, 256, 0, stream>>>(partial, (float*)d_out, nblk, inv_total);
}

// Round 2
// 187.865 us; speedup vs baseline: 1.1634x; 1.1634x over previous
//
#include <hip/hip_runtime.h>

namespace {
constexpr int IMG_W = 512, IMG_H = 512;
constexpr int TW = 32, TH = 32;
constexpr int IN_W = TW + 10, IN_H = TH + 10;   // 42
constexpr int S12_STR = 43;   // float2 stride: 86 dw ≡ 22 mod 32 -> 2-way max in phase 2
constexpr int H12_STR = 35;   // float2 stride: 70 dw ≡ 6 mod 32  -> 2-way max
constexpr int HAB_STR = 33;   // float stride:  33 ≡ 1 mod 32     -> 2-way max
constexpr float C1c = 0.01f * 0.01f;
constexpr float C2c = 0.03f * 0.03f;

// Gaussian(sigma=1.5, K=11), normalized; sum == 1.0
constexpr float GW[11] = {
    1.0283799e-03f, 7.5987582e-03f, 3.6000773e-02f, 1.0936069e-01f,
    2.1300554e-01f, 2.6601172e-01f, 2.1300554e-01f, 1.0936069e-01f,
    3.6000773e-02f, 7.5987582e-03f, 1.0283799e-03f
};

__device__ __forceinline__ float2 fma2(float w, float2 a, float2 c) {
    return make_float2(fmaf(w, a.x, c.x), fmaf(w, a.y, c.y));
}
__device__ __forceinline__ float2 mul2(float2 a, float2 b) {
    return make_float2(a.x * b.x, a.y * b.y);
}
}

// LDS 29.1 KB (union: h-planes alias dead s12) -> 4-5 blocks/CU by LDS.
// launch_bounds(256,4): 4 waves/EU -> VGPR cap 128; phase-2 live set ~110 fits.
__global__ __launch_bounds__(256, 4) void ssim_tile_kernel(
        const float* __restrict__ img1, const float* __restrict__ img2,
        double* __restrict__ acc)
{
    union SharedU {
        float2 s12[IN_H * S12_STR];                 // 14448 B
        struct {
            float2 h12 [IN_H * H12_STR];            // 11760 B  (mu1,mu2)
            float2 hsq [IN_H * H12_STR];            // 11760 B  (E[x2],E[y2])
            float  hab [IN_H * HAB_STR];            //  5544 B  (E[xy])
        } h;                                        // 29064 B total
    };
    __shared__ SharedU u;
    __shared__ float wred[4];

    const int tid = threadIdx.x;
    const size_t base = (size_t)blockIdx.z * (IMG_W * IMG_H);
    const float* p1 = img1 + base;
    const float* p2 = img2 + base;
    const int x0 = blockIdx.x * TW - 5;
    const int y0 = blockIdx.y * TH - 5;

    // ---- Phase 1: global -> LDS; interior blocks skip bounds checks ----
    if (blockIdx.x > 0 && blockIdx.x < gridDim.x - 1 &&
        blockIdx.y > 0 && blockIdx.y < gridDim.y - 1) {
        for (int p = tid; p < IN_H * IN_W; p += 256) {
            const int r = p / IN_W, c = p - r * IN_W;
            const int off = (y0 + r) * IMG_W + (x0 + c);
            u.s12[r * S12_STR + c] = make_float2(p1[off], p2[off]);
        }
    } else {
        for (int p = tid; p < IN_H * IN_W; p += 256) {
            const int r = p / IN_W, c = p - r * IN_W;
            const int gy = y0 + r, gx = x0 + c;
            float a = 0.f, b = 0.f;
            if (gy >= 0 && gy < IMG_H && gx >= 0 && gx < IMG_W) {
                const int off = gy * IMG_W + gx;
                a = p1[off]; b = p2[off];
            }
            u.s12[r * S12_STR + c] = make_float2(a, b);
        }
    }
    __syncthreads();

    // ---- Phase 2: horizontal 11-tap, results in registers across barrier ----
    // 42 rows x 4 col-groups x 8 outputs = 168 active threads
    const int r2 = tid >> 2;
    const int cb = (tid & 3) * 8;
    float2 m12[8], sq2[8];
    float  sx1[8];
    if (tid < 168) {
        float2 v[18];
#pragma unroll
        for (int k = 0; k < 18; ++k) v[k] = u.s12[r2 * S12_STR + cb + k];
        float2 aa[18]; float ab[18];
#pragma unroll
        for (int k = 0; k < 18; ++k) {
            aa[k] = mul2(v[k], v[k]);
            ab[k] = v[k].x * v[k].y;
        }
#pragma unroll
        for (int j = 0; j < 8; ++j) {
            float2 m = make_float2(0.f, 0.f), s = make_float2(0.f, 0.f);
            float c3 = 0.f;
#pragma unroll
            for (int k = 0; k < 11; ++k) {
                const float wk = GW[k];
                m  = fma2(wk, v [j + k], m);
                s  = fma2(wk, aa[j + k], s);
                c3 = fmaf(wk, ab[j + k], c3);
            }
            m12[j] = m; sq2[j] = s; sx1[j] = c3;
        }
    }
    __syncthreads();            // all reads of s12 done; safe to overwrite
    if (tid < 168) {
#pragma unroll
        for (int j = 0; j < 8; ++j) {
            u.h.h12[r2 * H12_STR + cb + j] = m12[j];
            u.h.hsq[r2 * H12_STR + cb + j] = sq2[j];
            u.h.hab[r2 * HAB_STR + cb + j] = sx1[j];
        }
    }
    __syncthreads();

    // ---- Phase 3: vertical 11-tap + SSIM, 4 rows per thread ----
    const int c  = tid & 31;
    const int rb = (tid >> 5) * 4;
    float2 hm[14], hs[14]; float hx[14];
#pragma unroll
    for (int k = 0; k < 14; ++k) {
        hm[k] = u.h.h12[(rb + k) * H12_STR + c];
        hs[k] = u.h.hsq[(rb + k) * H12_STR + c];
        hx[k] = u.h.hab[(rb + k) * HAB_STR + c];
    }
    float lsum = 0.f;
#pragma unroll
    for (int j = 0; j < 4; ++j) {
        float2 mu = make_float2(0.f, 0.f), sg = make_float2(0.f, 0.f);
        float sxy = 0.f;
#pragma unroll
        for (int k = 0; k < 11; ++k) {
            const float wk = GW[k];
            mu  = fma2(wk, hm[j + k], mu);
            sg  = fma2(wk, hs[j + k], sg);
            sxy = fmaf(wk, hx[j + k], sxy);
        }
        const float mu1s = mu.x * mu.x, mu2s = mu.y * mu.y, mu12 = mu.x * mu.y;
        const float s1 = sg.x - mu1s, s2 = sg.y - mu2s, s12v = sxy - mu12;
        const float num = (2.f * mu12 + C1c) * (2.f * s12v + C2c);
        const float den = (mu1s + mu2s + C1c) * (s1 + s2 + C2c);
        lsum += __fdividef(num, den);
    }

    // ---- Phase 4: block reduce -> double atomic into 256 ws slots ----
#pragma unroll
    for (int off = 32; off > 0; off >>= 1)
        lsum += __shfl_down(lsum, off, 64);
    if ((tid & 63) == 0) wred[tid >> 6] = lsum;
    __syncthreads();
    if (tid == 0) {
        const int bid = (blockIdx.z * gridDim.y + blockIdx.y) * gridDim.x + blockIdx.x;
        unsafeAtomicAdd(&acc[bid & 255],
                        (double)(wred[0] + wred[1] + wred[2] + wred[3]));
    }
}

__global__ __launch_bounds__(256) void ssim_final_kernel(
        const double* __restrict__ acc, float* __restrict__ out, double inv_total)
{
    const int tid = threadIdx.x;
    double a = acc[tid];
#pragma unroll
    for (int off = 32; off > 0; off >>= 1)
        a += __shfl_down(a, off, 64);
    __shared__ double ws[4];
    if ((tid & 63) == 0) ws[tid >> 6] = a;
    __syncthreads();
    if (tid == 0)
        out[0] = (float)((ws[0] + ws[1] + ws[2] + ws[3]) * inv_total);
}

extern "C" void kernel_launch(void* const* d_in, const int* in_sizes, int n_in,
                              void* d_out, int out_size, void* d_ws, size_t ws_size,
                              hipStream_t stream)
{
    const float* img1 = (const float*)d_in[0];
    const float* img2 = (const float*)d_in[1];
    double* acc = (double*)d_ws;

    hipMemsetAsync(d_ws, 0, 256 * sizeof(double), stream);  // capturable memset node

    const int nch = in_sizes[0] / (IMG_W * IMG_H);      // 16*3 = 48
    dim3 grid(IMG_W / TW, IMG_H / TH, nch);             // 16 x 16 x 48
    ssim_tile_kernel<<<grid, 256, 0, stream>>>(img1, img2, acc);

    const double inv_total = 1.0 / (double)in_sizes[0];
    ssim_final_kernel<<<1, 256, 0, stream>>>(acc, (float*)d_out, inv_total);
}

// Round 3
// 177.974 us; speedup vs baseline: 1.2280x; 1.0556x over previous
//
#include <hip/hip_runtime.h>

namespace {
constexpr int IMG_W = 512, IMG_H = 512;
constexpr int TW = 32, TH = 32;
constexpr int IN_W = TW + 10, IN_H = TH + 10;   // 42
constexpr int S12_STR = 46;  // float2 units; 92 dw ≡ 28 mod 32 -> b128 reads land on all
                             // 8 mult-of-4 start banks, 8 dw/bank = conflict-free min
constexpr int H4_STR  = 33;  // float4 units; write bank = 4(r2+j): 8 starts x 8 lanes,
                             // 8 dw/bank; read bank = 4(c+k): same -> conflict-free
constexpr int HAB_STR = 33;  // float units; bank = r+c pattern, 2/bank (free)
constexpr float C1c = 0.01f * 0.01f;
constexpr float C2c = 0.03f * 0.03f;

constexpr float GW[11] = {
    1.0283799e-03f, 7.5987582e-03f, 3.6000773e-02f, 1.0936069e-01f,
    2.1300554e-01f, 2.6601172e-01f, 2.1300554e-01f, 1.0936069e-01f,
    3.6000773e-02f, 7.5987582e-03f, 1.0283799e-03f
};

using v2f = __attribute__((ext_vector_type(2))) float;
using v4f = __attribute__((ext_vector_type(4))) float;

__device__ __forceinline__ v2f fma2(float w, v2f a, v2f c) {
    v2f r;
    r.x = fmaf(w, a.x, c.x);
    r.y = fmaf(w, a.y, c.y);
    return r;
}
}

// LDS union: s12 (15456 B) aliased by h4+hab (27720 B) -> 27.7 KB/block,
// 5 blocks/CU by LDS; launch_bounds(256,5) lifts the wave cap to match.
__global__ __launch_bounds__(256, 5) void ssim_tile_kernel(
        const float* __restrict__ img1, const float* __restrict__ img2,
        double* __restrict__ acc)
{
    union SharedU {
        v2f s12[IN_H * S12_STR];                // 15456 B
        struct {
            v4f   h4 [IN_H * H4_STR];           // 22176 B (mu1,mu2,Exx,Eyy)
            float hab[IN_H * HAB_STR];          //  5544 B (Exy)
        } h;
    };
    __shared__ SharedU u;
    __shared__ float wred[4];

    const int tid = threadIdx.x;
    const size_t base = (size_t)blockIdx.z * (IMG_W * IMG_H);
    const float* p1 = img1 + base;
    const float* p2 = img2 + base;
    const int x0 = blockIdx.x * TW - 5;
    const int y0 = blockIdx.y * TH - 5;

    // ---- Phase 1: global -> LDS; interior blocks skip bounds checks ----
    if (blockIdx.x > 0 && blockIdx.x < gridDim.x - 1 &&
        blockIdx.y > 0 && blockIdx.y < gridDim.y - 1) {
#pragma unroll
        for (int i = 0; i < 7; ++i) {
            const int p = tid + i * 256;
            if (p < IN_H * IN_W) {
                const int r = p / IN_W, c = p - r * IN_W;
                const int off = (y0 + r) * IMG_W + (x0 + c);
                v2f t; t.x = p1[off]; t.y = p2[off];
                u.s12[r * S12_STR + c] = t;
            }
        }
    } else {
#pragma unroll
        for (int i = 0; i < 7; ++i) {
            const int p = tid + i * 256;
            if (p < IN_H * IN_W) {
                const int r = p / IN_W, c = p - r * IN_W;
                const int gy = y0 + r, gx = x0 + c;
                v2f t; t.x = 0.f; t.y = 0.f;
                if (gy >= 0 && gy < IMG_H && gx >= 0 && gx < IMG_W) {
                    const int off = gy * IMG_W + gx;
                    t.x = p1[off]; t.y = p2[off];
                }
                u.s12[r * S12_STR + c] = t;
            }
        }
    }
    __syncthreads();

    // ---- Phase 2: horizontal 11-tap, results in registers across barrier ----
    // 42 rows x 4 col-groups x 8 outputs = 168 active threads
    const int r2 = tid >> 2;
    const int cb = (tid & 3) * 8;
    v2f m12[8], sq2[8];
    float sx1[8];
    if (tid < 168) {
        // 9 aligned b128 loads -> 18-wide float2 sliding window
        const v4f* srow = (const v4f*)&u.s12[r2 * S12_STR + cb];
        v2f v[18];
#pragma unroll
        for (int m = 0; m < 9; ++m) {
            const v4f q = srow[m];
            v2f a; a.x = q.x; a.y = q.y;
            v2f b; b.x = q.z; b.y = q.w;
            v[2 * m]     = a;
            v[2 * m + 1] = b;
        }
        v2f aa[18]; float ab[18];
#pragma unroll
        for (int k = 0; k < 18; ++k) {
            aa[k] = v[k] * v[k];
            ab[k] = v[k].x * v[k].y;
        }
#pragma unroll
        for (int j = 0; j < 8; ++j) {
            v2f m; m.x = 0.f; m.y = 0.f;
            v2f s; s.x = 0.f; s.y = 0.f;
            float c3 = 0.f;
#pragma unroll
            for (int k = 0; k < 11; ++k) {
                const float wk = GW[k];
                m  = fma2(wk, v [j + k], m);
                s  = fma2(wk, aa[j + k], s);
                c3 = fmaf(wk, ab[j + k], c3);
            }
            m12[j] = m; sq2[j] = s; sx1[j] = c3;
        }
    }
    __syncthreads();            // all reads of s12 done; safe to overwrite
    if (tid < 168) {
#pragma unroll
        for (int j = 0; j < 8; ++j) {
            v4f q;
            q.x = m12[j].x; q.y = m12[j].y;
            q.z = sq2[j].x; q.w = sq2[j].y;
            u.h.h4 [r2 * H4_STR  + cb + j] = q;
            u.h.hab[r2 * HAB_STR + cb + j] = sx1[j];
        }
    }
    __syncthreads();

    // ---- Phase 3: vertical 11-tap + SSIM, 4 rows per thread ----
    const int c  = tid & 31;
    const int rb = (tid >> 5) * 4;
    v2f hm[14], hs[14]; float hx[14];
#pragma unroll
    for (int k = 0; k < 14; ++k) {
        const v4f q = u.h.h4[(rb + k) * H4_STR + c];
        v2f a; a.x = q.x; a.y = q.y;
        v2f b; b.x = q.z; b.y = q.w;
        hm[k] = a; hs[k] = b;
        hx[k] = u.h.hab[(rb + k) * HAB_STR + c];
    }
    float lsum = 0.f;
#pragma unroll
    for (int j = 0; j < 4; ++j) {
        v2f mu; mu.x = 0.f; mu.y = 0.f;
        v2f sg; sg.x = 0.f; sg.y = 0.f;
        float sxy = 0.f;
#pragma unroll
        for (int k = 0; k < 11; ++k) {
            const float wk = GW[k];
            mu  = fma2(wk, hm[j + k], mu);
            sg  = fma2(wk, hs[j + k], sg);
            sxy = fmaf(wk, hx[j + k], sxy);
        }
        const float mu1s = mu.x * mu.x, mu2s = mu.y * mu.y, mu12 = mu.x * mu.y;
        const float s1 = sg.x - mu1s, s2 = sg.y - mu2s, s12v = sxy - mu12;
        const float num = (2.f * mu12 + C1c) * (2.f * s12v + C2c);
        const float den = (mu1s + mu2s + C1c) * (s1 + s2 + C2c);
        lsum += __fdividef(num, den);
    }

    // ---- Phase 4: block reduce -> double atomic into 256 ws slots ----
#pragma unroll
    for (int off = 32; off > 0; off >>= 1)
        lsum += __shfl_down(lsum, off, 64);
    if ((tid & 63) == 0) wred[tid >> 6] = lsum;
    __syncthreads();
    if (tid == 0) {
        const int bid = (blockIdx.z * gridDim.y + blockIdx.y) * gridDim.x + blockIdx.x;
        unsafeAtomicAdd(&acc[bid & 255],
                        (double)(wred[0] + wred[1] + wred[2] + wred[3]));
    }
}

__global__ __launch_bounds__(256) void ssim_final_kernel(
        const double* __restrict__ acc, float* __restrict__ out, double inv_total)
{
    const int tid = threadIdx.x;
    double a = acc[tid];
#pragma unroll
    for (int off = 32; off > 0; off >>= 1)
        a += __shfl_down(a, off, 64);
    __shared__ double ws[4];
    if ((tid & 63) == 0) ws[tid >> 6] = a;
    __syncthreads();
    if (tid == 0)
        out[0] = (float)((ws[0] + ws[1] + ws[2] + ws[3]) * inv_total);
}

extern "C" void kernel_launch(void* const* d_in, const int* in_sizes, int n_in,
                              void* d_out, int out_size, void* d_ws, size_t ws_size,
                              hipStream_t stream)
{
    const float* img1 = (const float*)d_in[0];
    const float* img2 = (const float*)d_in[1];
    double* acc = (double*)d_ws;

    hipMemsetAsync(d_ws, 0, 256 * sizeof(double), stream);

    const int nch = in_sizes[0] / (IMG_W * IMG_H);      // 16*3 = 48
    dim3 grid(IMG_W / TW, IMG_H / TH, nch);             // 16 x 16 x 48
    ssim_tile_kernel<<<grid, 256, 0, stream>>>(img1, img2, acc);

    const double inv_total = 1.0 / (double)in_sizes[0];
    ssim_final_kernel<<<1, 256, 0, stream>>>(acc, (float*)d_out, inv_total);
}

// Round 4
// 171.252 us; speedup vs baseline: 1.2762x; 1.0393x over previous
//
#include <hip/hip_runtime.h>

namespace {
constexpr int IMG_W = 512, IMG_H = 512;
constexpr int TW = 32, TH = 32;
constexpr int IN_W = TW + 10, IN_H = TH + 10;   // 42
constexpr int S12_STR = 46;  // float2 units
constexpr int H4_STR  = 33;  // float4 units
constexpr int HAB_STR = 33;  // float units
constexpr float C1c = 0.01f * 0.01f;
constexpr float C2c = 0.03f * 0.03f;

constexpr float GW[11] = {
    1.0283799e-03f, 7.5987582e-03f, 3.6000773e-02f, 1.0936069e-01f,
    2.1300554e-01f, 2.6601172e-01f, 2.1300554e-01f, 1.0936069e-01f,
    3.6000773e-02f, 7.5987582e-03f, 1.0283799e-03f
};

using v2f = __attribute__((ext_vector_type(2))) float;
using v4f = __attribute__((ext_vector_type(4))) float;

// Forced packed fp32 math (VOP3P, gfx90a+): one issue for two lanes' FMA.
__device__ __forceinline__ v2f pkfma(v2f a, v2f b, v2f c) {
    v2f d;
    asm("v_pk_fma_f32 %0, %1, %2, %3" : "=v"(d) : "v"(a), "v"(b), "v"(c));
    return d;
}
__device__ __forceinline__ v2f pkmul(v2f a, v2f b) {
    v2f d;
    asm("v_pk_mul_f32 %0, %1, %2" : "=v"(d) : "v"(a), "v"(b));
    return d;
}
__device__ __forceinline__ v2f bcast(float w) { v2f r; r.x = w; r.y = w; return r; }
}

// LDS union 27.7 KB -> 5 blocks/CU; (256,5) caps VGPR at ~96 which the
// scatter-form accumulators (40 dw phase2 / 20 dw phase3) fit comfortably.
__global__ __launch_bounds__(256, 5) void ssim_tile_kernel(
        const float* __restrict__ img1, const float* __restrict__ img2,
        double* __restrict__ acc)
{
    union SharedU {
        v2f s12[IN_H * S12_STR];                // 15456 B
        struct {
            v4f   h4 [IN_H * H4_STR];           // 22176 B (mu1,mu2,Exx,Eyy)
            float hab[IN_H * HAB_STR];          //  5544 B (Exy)
        } h;
    };
    __shared__ SharedU u;
    __shared__ float wred[4];

    const int tid = threadIdx.x;
    const size_t base = (size_t)blockIdx.z * (IMG_W * IMG_H);
    const float* p1 = img1 + base;
    const float* p2 = img2 + base;
    const int x0 = blockIdx.x * TW - 5;
    const int y0 = blockIdx.y * TH - 5;

    // ---- Phase 1: global -> LDS; interior blocks skip bounds checks ----
    if (blockIdx.x > 0 && blockIdx.x < gridDim.x - 1 &&
        blockIdx.y > 0 && blockIdx.y < gridDim.y - 1) {
#pragma unroll
        for (int i = 0; i < 7; ++i) {
            const int p = tid + i * 256;
            if (p < IN_H * IN_W) {
                const int r = p / IN_W, c = p - r * IN_W;
                const int off = (y0 + r) * IMG_W + (x0 + c);
                v2f t; t.x = p1[off]; t.y = p2[off];
                u.s12[r * S12_STR + c] = t;
            }
        }
    } else {
#pragma unroll
        for (int i = 0; i < 7; ++i) {
            const int p = tid + i * 256;
            if (p < IN_H * IN_W) {
                const int r = p / IN_W, c = p - r * IN_W;
                const int gy = y0 + r, gx = x0 + c;
                v2f t; t.x = 0.f; t.y = 0.f;
                if (gy >= 0 && gy < IMG_H && gx >= 0 && gx < IMG_W) {
                    const int off = gy * IMG_W + gx;
                    t.x = p1[off]; t.y = p2[off];
                }
                u.s12[r * S12_STR + c] = t;
            }
        }
    }
    __syncthreads();

    // ---- Phase 2: horizontal 11-tap, scatter form (taps outer, acc live) ----
    // 42 rows x 4 col-groups x 8 outputs = 168 active threads
    const int r2 = tid >> 2;
    const int cb = (tid & 3) * 8;
    v2f mu8[8], sq8[8];
    float xy8[8];
    if (tid < 168) {
#pragma unroll
        for (int j = 0; j < 8; ++j) {
            mu8[j] = bcast(0.f); sq8[j] = bcast(0.f); xy8[j] = 0.f;
        }
        const v4f* srow = (const v4f*)&u.s12[r2 * S12_STR + cb];
#pragma unroll
        for (int m = 0; m < 9; ++m) {
            const v4f q = srow[m];
#pragma unroll
            for (int half = 0; half < 2; ++half) {
                const int k = 2 * m + half;
                v2f v;
                v.x = half ? q.z : q.x;
                v.y = half ? q.w : q.y;
                const v2f a2 = pkmul(v, v);
                const float xyv = v.x * v.y;
#pragma unroll
                for (int j = 0; j < 8; ++j) {
                    const int t = k - j;
                    if (t >= 0 && t < 11) {
                        const v2f w2 = bcast(GW[t]);
                        mu8[j] = pkfma(w2, v,  mu8[j]);
                        sq8[j] = pkfma(w2, a2, sq8[j]);
                        xy8[j] = fmaf(GW[t], xyv, xy8[j]);
                    }
                }
            }
        }
    }
    __syncthreads();            // all reads of s12 done; safe to overwrite
    if (tid < 168) {
#pragma unroll
        for (int j = 0; j < 8; ++j) {
            v4f q;
            q.x = mu8[j].x; q.y = mu8[j].y;
            q.z = sq8[j].x; q.w = sq8[j].y;
            u.h.h4 [r2 * H4_STR  + cb + j] = q;
            u.h.hab[r2 * HAB_STR + cb + j] = xy8[j];
        }
    }
    __syncthreads();

    // ---- Phase 3: vertical 11-tap + SSIM, scatter form, 4 rows/thread ----
    const int c  = tid & 31;
    const int rb = (tid >> 5) * 4;
    v2f mu4[4], sg4[4];
    float xy4[4];
#pragma unroll
    for (int j = 0; j < 4; ++j) {
        mu4[j] = bcast(0.f); sg4[j] = bcast(0.f); xy4[j] = 0.f;
    }
#pragma unroll
    for (int k = 0; k < 14; ++k) {
        const v4f q = u.h.h4[(rb + k) * H4_STR + c];
        const float hx = u.h.hab[(rb + k) * HAB_STR + c];
        v2f hm; hm.x = q.x; hm.y = q.y;
        v2f hs; hs.x = q.z; hs.y = q.w;
#pragma unroll
        for (int j = 0; j < 4; ++j) {
            const int t = k - j;
            if (t >= 0 && t < 11) {
                const v2f w2 = bcast(GW[t]);
                mu4[j] = pkfma(w2, hm, mu4[j]);
                sg4[j] = pkfma(w2, hs, sg4[j]);
                xy4[j] = fmaf(GW[t], hx, xy4[j]);
            }
        }
    }
    float lsum = 0.f;
#pragma unroll
    for (int j = 0; j < 4; ++j) {
        const float mu1s = mu4[j].x * mu4[j].x;
        const float mu2s = mu4[j].y * mu4[j].y;
        const float mu12 = mu4[j].x * mu4[j].y;
        const float s1 = sg4[j].x - mu1s, s2 = sg4[j].y - mu2s, s12v = xy4[j] - mu12;
        const float num = (2.f * mu12 + C1c) * (2.f * s12v + C2c);
        const float den = (mu1s + mu2s + C1c) * (s1 + s2 + C2c);
        lsum += __fdividef(num, den);
    }

    // ---- Phase 4: block reduce -> double atomic into 256 ws slots ----
#pragma unroll
    for (int off = 32; off > 0; off >>= 1)
        lsum += __shfl_down(lsum, off, 64);
    if ((tid & 63) == 0) wred[tid >> 6] = lsum;
    __syncthreads();
    if (tid == 0) {
        const int bid = (blockIdx.z * gridDim.y + blockIdx.y) * gridDim.x + blockIdx.x;
        unsafeAtomicAdd(&acc[bid & 255],
                        (double)(wred[0] + wred[1] + wred[2] + wred[3]));
    }
}

__global__ __launch_bounds__(256) void ssim_final_kernel(
        const double* __restrict__ acc, float* __restrict__ out, double inv_total)
{
    const int tid = threadIdx.x;
    double a = acc[tid];
#pragma unroll
    for (int off = 32; off > 0; off >>= 1)
        a += __shfl_down(a, off, 64);
    __shared__ double ws[4];
    if ((tid & 63) == 0) ws[tid >> 6] = a;
    __syncthreads();
    if (tid == 0)
        out[0] = (float)((ws[0] + ws[1] + ws[2] + ws[3]) * inv_total);
}

extern "C" void kernel_launch(void* const* d_in, const int* in_sizes, int n_in,
                              void* d_out, int out_size, void* d_ws, size_t ws_size,
                              hipStream_t stream)
{
    const float* img1 = (const float*)d_in[0];
    const float* img2 = (const float*)d_in[1];
    double* acc = (double*)d_ws;

    hipMemsetAsync(d_ws, 0, 256 * sizeof(double), stream);

    const int nch = in_sizes[0] / (IMG_W * IMG_H);      // 16*3 = 48
    dim3 grid(IMG_W / TW, IMG_H / TH, nch);             // 16 x 16 x 48
    ssim_tile_kernel<<<grid, 256, 0, stream>>>(img1, img2, acc);

    const double inv_total = 1.0 / (double)in_sizes[0];
    ssim_final_kernel<<<1, 256, 0, stream>>>(acc, (float*)d_out, inv_total);
}